// Round 1
// baseline (771.698 us; speedup 1.0000x reference)
//
#include <hip/hip_runtime.h>

#define B_TOT 8192
#define T_OBS 128
#define T_FUT 64
#define T_ALL 192
#define DIN 5
#define HD 128

typedef __attribute__((ext_vector_type(8))) short short8;
typedef __attribute__((ext_vector_type(4))) float f32x4;

__device__ inline short f2bf(float f) {
    unsigned u = __float_as_uint(f);
    u += 0x7FFFu + ((u >> 16) & 1u);   // round-to-nearest-even
    return (short)(u >> 16);
}

__device__ inline float sigm(float x) {
    return __builtin_amdgcn_rcpf(1.f + __expf(-x));
}
__device__ inline float tanh_(float x) {
    return 1.f - 2.f * __builtin_amdgcn_rcpf(1.f + __expf(2.f * x));
}

__device__ inline f32x4 MFMA(short8 a, short8 b, f32x4 c) {
    return __builtin_amdgcn_mfma_f32_16x16x32_bf16(a, b, c, 0, 0, 0);
}

__device__ inline short8 load_w8(const float* p) {
    float4 a = *reinterpret_cast<const float4*>(p);
    float4 b = *reinterpret_cast<const float4*>(p + 4);
    short8 r;
    r[0] = f2bf(a.x); r[1] = f2bf(a.y); r[2] = f2bf(a.z); r[3] = f2bf(a.w);
    r[4] = f2bf(b.x); r[5] = f2bf(b.y); r[6] = f2bf(b.z); r[7] = f2bf(b.w);
    return r;
}
__device__ inline short8 load_w5(const float* p) {
    short8 r = (short8)0;
    r[0] = f2bf(p[0]); r[1] = f2bf(p[1]); r[2] = f2bf(p[2]);
    r[3] = f2bf(p[3]); r[4] = f2bf(p[4]);
    return r;
}

__global__ __launch_bounds__(256, 2)
void gru_tracemodel_kernel(const float* __restrict__ obs, const float* __restrict__ target,
                           const float* __restrict__ eWih, const float* __restrict__ eWhh,
                           const float* __restrict__ ebih, const float* __restrict__ ebhh,
                           const float* __restrict__ cWih, const float* __restrict__ cWhh,
                           const float* __restrict__ cbih, const float* __restrict__ cbhh,
                           const float* __restrict__ headW, const float* __restrict__ headb,
                           float* __restrict__ out)
{
    // double-buffered bf16 h staging; row stride 136 (pad 8) to spread LDS banks
    __shared__ __attribute__((aligned(16))) short Abuf[2][16][136];

    const int tid   = threadIdx.x;
    const int wave  = tid >> 6;
    const int lane  = tid & 63;
    const int q     = lane >> 4;   // quad index (A/B k-group, C/D row-group)
    const int c     = lane & 15;   // col-in-tile / A row
    const int b0    = blockIdx.x * 16;
    const int wbase = wave * 32;   // this wave's j-slice [wbase, wbase+32)

    // zero buf 0 (h0 = 0)
    for (int i = tid; i < 16 * 136; i += 256) ((short*)Abuf)[i] = 0;

    // ---- weight fragments in registers (B-operand: lane holds W'[n = base+c][k = kt*32+q*8+j]) ----
    short8 Wrz[2][2][5];  // [gate r/z][jt][ktile 0..4]; ktile 4 = x part (Wih)
    short8 Wnh[2][4];     // n-gate, Whh part
    short8 Wnx[2];        // n-gate, Wih part
    float  brz[2][2], bnh[2], bni[2];

    auto load_phase = [&](const float* Wih, const float* Whh,
                          const float* bih, const float* bhh) {
        #pragma unroll
        for (int g = 0; g < 2; ++g)
            #pragma unroll
            for (int jt = 0; jt < 2; ++jt) {
                int n = g * 128 + wbase + jt * 16 + c;
                #pragma unroll
                for (int kt = 0; kt < 4; ++kt)
                    Wrz[g][jt][kt] = load_w8(Whh + n * HD + kt * 32 + q * 8);
                Wrz[g][jt][4] = (q == 0) ? load_w5(Wih + n * DIN) : (short8)0;
                brz[g][jt] = bih[n] + bhh[n];
            }
        #pragma unroll
        for (int jt = 0; jt < 2; ++jt) {
            int n = 256 + wbase + jt * 16 + c;
            #pragma unroll
            for (int kt = 0; kt < 4; ++kt)
                Wnh[jt][kt] = load_w8(Whh + n * HD + kt * 32 + q * 8);
            Wnx[jt] = (q == 0) ? load_w5(Wih + n * DIN) : (short8)0;
            bnh[jt] = bhh[n];
            bni[jt] = bih[n];
        }
    };
    load_phase(eWih, eWhh, ebih, ebhh);

    // head fragments (wave 0 only): B[k][d] with d = c (<5), from headW[d][k]
    short8 Whd[4];
    float  hb = 0.f;
    if (wave == 0) {
        #pragma unroll
        for (int kt = 0; kt < 4; ++kt)
            Whd[kt] = (c < DIN) ? load_w8(headW + c * HD + kt * 32 + q * 8) : (short8)0;
        hb = (c < DIN) ? headb[c] : 0.f;
    }

    // fp32 carried hidden state: h[q*4+r][wbase + jt*16 + c]
    float hreg[2][4] = {{0.f, 0.f, 0.f, 0.f}, {0.f, 0.f, 0.f, 0.f}};

    const float* obs_row = obs    + (size_t)(b0 + c) * (T_OBS * DIN);
    const float* tgt_row = target + (size_t)(b0 + c) * (T_FUT * DIN);
    float x5[5] = {0.f, 0.f, 0.f, 0.f, 0.f};
    if (q == 0) {
        #pragma unroll
        for (int j = 0; j < DIN; ++j) x5[j] = obs_row[j];   // x_0
    }

    for (int t = 0; t <= T_ALL; ++t) {
        __syncthreads();
        const int p = t & 1;

        // A h-fragments: lane holds h[m=c][k = kt*32+q*8 .. +7] (bf16 from LDS)
        short8 ah[4];
        const short* ap = &Abuf[p][c][0];
        #pragma unroll
        for (int kt = 0; kt < 4; ++kt)
            ah[kt] = *reinterpret_cast<const short8*>(ap + kt * 32 + q * 8);

        // fused head: ah holds h of previous iteration = rollout h_{t-129}
        if (wave == 0 && t >= T_OBS + 1) {
            f32x4 acc = {hb, hb, hb, hb};
            #pragma unroll
            for (int kt = 0; kt < 4; ++kt)
                acc = MFMA(ah[kt], Whd[kt], acc);
            if (c < DIN) {
                int s = t - (T_OBS + 1);
                #pragma unroll
                for (int r = 0; r < 4; ++r) {
                    int m = q * 4 + r;
                    out[((size_t)(b0 + m) * T_FUT + s) * DIN + c] = acc[r];
                }
            }
        }
        if (t == T_ALL) break;

        if (t == T_OBS) load_phase(cWih, cWhh, cbih, cbhh);  // switch to cell weights

        // x fragment (5th K-tile): lanes q==0 hold x[m=c][0..4], rest zero
        short8 ax = (short8)0;
        if (q == 0) {
            #pragma unroll
            for (int j = 0; j < DIN; ++j) ax[j] = f2bf(x5[j]);
            int tn = t + 1;   // prefetch next step's x
            if (tn < T_ALL) {
                const float* px = (tn < T_OBS)  ? (obs_row + tn * DIN)
                                : (tn == T_OBS) ? (obs_row + (T_OBS - 1) * DIN)
                                                : (tgt_row + (tn - T_OBS - 1) * DIN);
                #pragma unroll
                for (int j = 0; j < DIN; ++j) x5[j] = px[j];
            }
        }

        // gate MFMAs: 30 per wave
        f32x4 aR[2], aZ[2], aNh[2], aNi[2];
        #pragma unroll
        for (int jt = 0; jt < 2; ++jt) {
            aR[jt]  = {brz[0][jt], brz[0][jt], brz[0][jt], brz[0][jt]};
            aZ[jt]  = {brz[1][jt], brz[1][jt], brz[1][jt], brz[1][jt]};
            aNh[jt] = {bnh[jt], bnh[jt], bnh[jt], bnh[jt]};
            aNi[jt] = {bni[jt], bni[jt], bni[jt], bni[jt]};
            #pragma unroll
            for (int kt = 0; kt < 4; ++kt) {
                aR[jt]  = MFMA(ah[kt], Wrz[0][jt][kt], aR[jt]);
                aZ[jt]  = MFMA(ah[kt], Wrz[1][jt][kt], aZ[jt]);
                aNh[jt] = MFMA(ah[kt], Wnh[jt][kt],    aNh[jt]);
            }
            aR[jt]  = MFMA(ax, Wrz[0][jt][4], aR[jt]);
            aZ[jt]  = MFMA(ax, Wrz[1][jt][4], aZ[jt]);
            aNi[jt] = MFMA(ax, Wnx[jt],       aNi[jt]);
        }

        // elementwise GRU update (lane-local: same lane holds r,z,n,h for same (m,j))
        #pragma unroll
        for (int jt = 0; jt < 2; ++jt)
            #pragma unroll
            for (int r = 0; r < 4; ++r) {
                float rv = sigm(aR[jt][r]);
                float zv = sigm(aZ[jt][r]);
                float nv = tanh_(aNi[jt][r] + rv * aNh[jt][r]);
                float hn = nv + zv * (hreg[jt][r] - nv);  // (1-z)n + z h
                hreg[jt][r] = hn;
                Abuf[1 - p][q * 4 + r][wbase + jt * 16 + c] = f2bf(hn);
            }
    }
}

extern "C" void kernel_launch(void* const* d_in, const int* in_sizes, int n_in,
                              void* d_out, int out_size, void* d_ws, size_t ws_size,
                              hipStream_t stream)
{
    (void)in_sizes; (void)n_in; (void)d_ws; (void)ws_size; (void)out_size;
    gru_tracemodel_kernel<<<dim3(B_TOT / 16), dim3(256), 0, stream>>>(
        (const float*)d_in[0],  (const float*)d_in[1],
        (const float*)d_in[2],  (const float*)d_in[3],
        (const float*)d_in[4],  (const float*)d_in[5],
        (const float*)d_in[6],  (const float*)d_in[7],
        (const float*)d_in[8],  (const float*)d_in[9],
        (const float*)d_in[10], (const float*)d_in[11],
        (float*)d_out);
}

// Round 2
// 401.882 us; speedup vs baseline: 1.9202x; 1.9202x over previous
//
#include <hip/hip_runtime.h>

#define B_TOT 8192
#define T_OBS 128
#define T_FUT 64
#define T_ALL 192
#define DIN 5
#define HD 128
#define BT 32          // batch rows per block (two 16-row MFMA A-tiles)
#define LDSTR 136      // LDS row stride in shorts (pad 8 to spread banks)

typedef __attribute__((ext_vector_type(8))) short short8;
typedef __attribute__((ext_vector_type(4))) float f32x4;

__device__ inline short f2bf(float f) {
    unsigned u = __float_as_uint(f);
    u += 0x7FFFu + ((u >> 16) & 1u);   // round-to-nearest-even
    return (short)(u >> 16);
}

__device__ inline float sigm(float x) {
    return __builtin_amdgcn_rcpf(1.f + __expf(-x));
}
__device__ inline float tanh_(float x) {
    return 1.f - 2.f * __builtin_amdgcn_rcpf(1.f + __expf(2.f * x));
}

__device__ inline f32x4 MFMA(short8 a, short8 b, f32x4 c) {
    return __builtin_amdgcn_mfma_f32_16x16x32_bf16(a, b, c, 0, 0, 0);
}

__device__ inline short8 load_w8(const float* p) {
    float4 a = *reinterpret_cast<const float4*>(p);
    float4 b = *reinterpret_cast<const float4*>(p + 4);
    short8 r;
    r[0] = f2bf(a.x); r[1] = f2bf(a.y); r[2] = f2bf(a.z); r[3] = f2bf(a.w);
    r[4] = f2bf(b.x); r[5] = f2bf(b.y); r[6] = f2bf(b.z); r[7] = f2bf(b.w);
    return r;
}
__device__ inline short8 load_w5(const float* p) {
    short8 r = (short8)0;
    r[0] = f2bf(p[0]); r[1] = f2bf(p[1]); r[2] = f2bf(p[2]);
    r[3] = f2bf(p[3]); r[4] = f2bf(p[4]);
    return r;
}

// 512 threads = 8 waves. Wave w owns gate-columns [16w, 16w+16) of each of
// r/z/n. Block owns 32 batch rows as two 16-row A-tiles. Weights live in
// VGPRs: 15 short8 = 60 VGPRs/lane (fits; R1's 32-col slices spilled).
__global__ __launch_bounds__(512, 2)
void gru_tracemodel_kernel(const float* __restrict__ obs, const float* __restrict__ target,
                           const float* __restrict__ eWih, const float* __restrict__ eWhh,
                           const float* __restrict__ ebih, const float* __restrict__ ebhh,
                           const float* __restrict__ cWih, const float* __restrict__ cWhh,
                           const float* __restrict__ cbih, const float* __restrict__ cbhh,
                           const float* __restrict__ headW, const float* __restrict__ headb,
                           float* __restrict__ out)
{
    __shared__ __attribute__((aligned(16))) short Abuf[2][BT][LDSTR];

    const int tid   = threadIdx.x;
    const int wave  = tid >> 6;    // 0..7
    const int lane  = tid & 63;
    const int q     = lane >> 4;   // quad (A/B k-group, C/D row-group)
    const int c     = lane & 15;   // col-in-tile / A row
    const int b0    = blockIdx.x * BT;
    const int wbase = wave * 16;   // this wave's gate-column slice

    // h0 = 0
    for (int i = tid; i < 2 * BT * LDSTR; i += 512) ((short*)Abuf)[i] = 0;

    // ---- weight fragments (B-operand: lane holds W'[n][k = kt*32+q*8+j]) ----
    // kt 0..3: Whh K-tiles; kt 4: zero-padded Wih x-tile (only q==0 nonzero)
    short8 Wr[5], Wz[5], Wn[5];
    float  br, bz, bnh_, bni_;

    auto load_phase = [&](const float* Wih, const float* Whh,
                          const float* bih, const float* bhh) {
        const int nr = 0 * HD + wbase + c;
        const int nz = 1 * HD + wbase + c;
        const int nn = 2 * HD + wbase + c;
        #pragma unroll
        for (int kt = 0; kt < 4; ++kt) {
            Wr[kt] = load_w8(Whh + nr * HD + kt * 32 + q * 8);
            Wz[kt] = load_w8(Whh + nz * HD + kt * 32 + q * 8);
            Wn[kt] = load_w8(Whh + nn * HD + kt * 32 + q * 8);
        }
        Wr[4] = (q == 0) ? load_w5(Wih + nr * DIN) : (short8)0;
        Wz[4] = (q == 0) ? load_w5(Wih + nz * DIN) : (short8)0;
        Wn[4] = (q == 0) ? load_w5(Wih + nn * DIN) : (short8)0;
        br   = bih[nr] + bhh[nr];
        bz   = bih[nz] + bhh[nz];
        bnh_ = bhh[nn];
        bni_ = bih[nn];
    };
    load_phase(eWih, eWhh, ebih, ebhh);

    // head fragments (wave 0 only): B[k][d], d = c (<5), from headW[d][k]
    short8 Whd[4];
    float  hb = 0.f;
    if (wave == 0) {
        #pragma unroll
        for (int kt = 0; kt < 4; ++kt)
            Whd[kt] = (c < DIN) ? load_w8(headW + c * HD + kt * 32 + q * 8) : (short8)0;
        hb = (c < DIN) ? headb[c] : 0.f;
    }

    // fp32 carried h: hreg[a][r] = h[row a*16+q*4+r][wbase+c]
    float hreg[2][4] = {{0.f,0.f,0.f,0.f},{0.f,0.f,0.f,0.f}};

    const float* obsr[2] = { obs + (size_t)(b0 + c) * (T_OBS * DIN),
                             obs + (size_t)(b0 + 16 + c) * (T_OBS * DIN) };
    const float* tgtr[2] = { target + (size_t)(b0 + c) * (T_FUT * DIN),
                             target + (size_t)(b0 + 16 + c) * (T_FUT * DIN) };
    float x5[2][5] = {{0,0,0,0,0},{0,0,0,0,0}};
    if (q == 0) {
        #pragma unroll
        for (int a = 0; a < 2; ++a)
            #pragma unroll
            for (int j = 0; j < DIN; ++j) x5[a][j] = obsr[a][j];   // x_0
    }

    for (int t = 0; t <= T_ALL; ++t) {
        __syncthreads();
        const int p = t & 1;

        // A fragments: lane holds h[m = c (+16a)][k = kt*32+q*8 .. +7]
        short8 ah[2][4];
        #pragma unroll
        for (int a = 0; a < 2; ++a) {
            const short* ap = &Abuf[p][a * 16 + c][0];
            #pragma unroll
            for (int kt = 0; kt < 4; ++kt)
                ah[a][kt] = *reinterpret_cast<const short8*>(ap + kt * 32 + q * 8);
        }

        // fused head on previous step's h (rollout region)
        if (wave == 0 && t >= T_OBS + 1) {
            const int s = t - (T_OBS + 1);
            #pragma unroll
            for (int a = 0; a < 2; ++a) {
                f32x4 acc = {hb, hb, hb, hb};
                #pragma unroll
                for (int kt = 0; kt < 4; ++kt)
                    acc = MFMA(ah[a][kt], Whd[kt], acc);
                if (c < DIN) {
                    #pragma unroll
                    for (int r = 0; r < 4; ++r) {
                        int m = a * 16 + q * 4 + r;
                        out[((size_t)(b0 + m) * T_FUT + s) * DIN + c] = acc[r];
                    }
                }
            }
        }
        if (t == T_ALL) break;

        if (t == T_OBS) load_phase(cWih, cWhh, cbih, cbhh);  // switch to cell

        // x fragment (5th K-tile): q==0 lanes hold x[m][0..4]
        short8 ax[2] = {(short8)0, (short8)0};
        if (q == 0) {
            #pragma unroll
            for (int a = 0; a < 2; ++a)
                #pragma unroll
                for (int j = 0; j < DIN; ++j) ax[a][j] = f2bf(x5[a][j]);
            const int tn = t + 1;   // prefetch next step's x
            if (tn < T_ALL) {
                #pragma unroll
                for (int a = 0; a < 2; ++a) {
                    const float* px = (tn < T_OBS)  ? (obsr[a] + tn * DIN)
                                    : (tn == T_OBS) ? (obsr[a] + (T_OBS - 1) * DIN)
                                                    : (tgtr[a] + (tn - T_OBS - 1) * DIN);
                    #pragma unroll
                    for (int j = 0; j < DIN; ++j) x5[a][j] = px[j];
                }
            }
        }

        // gate MFMAs: 30/wave/step
        f32x4 aR[2], aZ[2], aNh[2], aNi[2];
        #pragma unroll
        for (int a = 0; a < 2; ++a) {
            aR[a]  = {br, br, br, br};
            aZ[a]  = {bz, bz, bz, bz};
            aNh[a] = {bnh_, bnh_, bnh_, bnh_};
            aNi[a] = {bni_, bni_, bni_, bni_};
            #pragma unroll
            for (int kt = 0; kt < 4; ++kt) {
                aR[a]  = MFMA(ah[a][kt], Wr[kt], aR[a]);
                aZ[a]  = MFMA(ah[a][kt], Wz[kt], aZ[a]);
                aNh[a] = MFMA(ah[a][kt], Wn[kt], aNh[a]);
            }
            aR[a]  = MFMA(ax[a], Wr[4], aR[a]);
            aZ[a]  = MFMA(ax[a], Wz[4], aZ[a]);
            aNi[a] = MFMA(ax[a], Wn[4], aNi[a]);
        }

        // elementwise GRU update (lane-local)
        #pragma unroll
        for (int a = 0; a < 2; ++a)
            #pragma unroll
            for (int r = 0; r < 4; ++r) {
                float rv = sigm(aR[a][r]);
                float zv = sigm(aZ[a][r]);
                float nv = tanh_(aNi[a][r] + rv * aNh[a][r]);
                float hn = nv + zv * (hreg[a][r] - nv);   // (1-z)n + z h
                hreg[a][r] = hn;
                Abuf[1 - p][a * 16 + q * 4 + r][wbase + c] = f2bf(hn);
            }
    }
}

extern "C" void kernel_launch(void* const* d_in, const int* in_sizes, int n_in,
                              void* d_out, int out_size, void* d_ws, size_t ws_size,
                              hipStream_t stream)
{
    (void)in_sizes; (void)n_in; (void)d_ws; (void)ws_size; (void)out_size;
    gru_tracemodel_kernel<<<dim3(B_TOT / BT), dim3(512), 0, stream>>>(
        (const float*)d_in[0],  (const float*)d_in[1],
        (const float*)d_in[2],  (const float*)d_in[3],
        (const float*)d_in[4],  (const float*)d_in[5],
        (const float*)d_in[6],  (const float*)d_in[7],
        (const float*)d_in[8],  (const float*)d_in[9],
        (const float*)d_in[10], (const float*)d_in[11],
        (float*)d_out);
}